// Round 3
// baseline (386.926 us; speedup 1.0000x reference)
//
#include <hip/hip_runtime.h>

// Output: [16, 46, 526, 518] f32.  Input: [16, 32, 512, 512] f32.
// Per output row (n,c,h):  out_row = [ in[1]x3 , in_row[0..511] , in[510]x3 ]
// where in_row = x[n, cmap(c), hmap(h), :].
//
// Structure: 256-thread blocks; 4 groups of 64 lanes; each group copies TWO
// rows (8 floats/lane/row = 2x dwordx4 loads). 4 independent loads in flight
// per thread before stores. Output stored non-temporally (write-once stream,
// keep L2 for the reused input rows).

using f4 = __attribute__((ext_vector_type(4))) float;

__device__ __forceinline__ int hmap(int d) {
    // reflect(+-2) -> edge(+-2) -> edge(+3 front) -> reflect(+3 front), H=512
    if (d <= 8)   return 2;
    if (d == 9)   return 1;
    if (d <= 521) return d - 10;
    return (d == 522) ? 510 : 509;
}

__device__ __forceinline__ int cmap(int g) {
    // wrap(+-1) -> wrap(+-3) -> edge(+3 back) -> reflect(+3 back), C=32
    if (g >= 43) g = 84 - g;   // reflect back pad (size 43)
    if (g > 39)  g = 39;       // edge clamp (size 40)
    int p = g - 3;             // wrap(+-3) on size 34
    if (p < 0)   p += 34;
    if (p >= 34) p -= 34;
    return (p == 0) ? 31 : ((p <= 32) ? (p - 1) : 0);  // wrap(+-1) on 32
}

__global__ __launch_bounds__(256) void pad_rows_kernel(const float* __restrict__ x,
                                                       float* __restrict__ out) {
    const int lane = threadIdx.x & 63;
    const int grp  = threadIdx.x >> 6;
    const int rowA = blockIdx.x * 8 + grp * 2;   // 8 rows per block
    const int rowB = rowA + 1;

    // Row A coords
    const int ncA = rowA / 526;          // magic-div
    const int hA  = rowA - ncA * 526;
    const int cA  = ncA % 46;
    const int nA  = ncA / 46;
    // Row B coords
    const int ncB = rowB / 526;
    const int hB  = rowB - ncB * 526;
    const int cB  = ncB % 46;
    const int nB  = ncB / 46;

    const float* inA = x + ((((size_t)nA * 32 + cmap(cA)) * 512 + hmap(hA)) << 9);
    const float* inB = x + ((((size_t)nB * 32 + cmap(cB)) * 512 + hmap(hB)) << 9);
    float* outA = out + (size_t)rowA * 518;
    float* outB = out + (size_t)rowB * 518;

    // 4 independent 16B loads (lane covers in[8l .. 8l+7] of each row)
    const f4 a0 = reinterpret_cast<const f4*>(inA)[2 * lane];
    const f4 a1 = reinterpret_cast<const f4*>(inA)[2 * lane + 1];
    const f4 b0 = reinterpret_cast<const f4*>(inB)[2 * lane];
    const f4 b1 = reinterpret_cast<const f4*>(inB)[2 * lane + 1];

    // Interior stores: out[3+8l .. 3+8l+7]
    __builtin_nontemporal_store(a0, reinterpret_cast<f4*>(outA + 3 + 8 * lane));
    __builtin_nontemporal_store(a1, reinterpret_cast<f4*>(outA + 7 + 8 * lane));
    __builtin_nontemporal_store(b0, reinterpret_cast<f4*>(outB + 3 + 8 * lane));
    __builtin_nontemporal_store(b1, reinterpret_cast<f4*>(outB + 7 + 8 * lane));

    if (lane == 0) {
        // out[0..2] = in[1]  (a0.y / b0.y)
        __builtin_nontemporal_store(a0.y, outA + 0);
        __builtin_nontemporal_store(a0.y, outA + 1);
        __builtin_nontemporal_store(a0.y, outA + 2);
        __builtin_nontemporal_store(b0.y, outB + 0);
        __builtin_nontemporal_store(b0.y, outB + 1);
        __builtin_nontemporal_store(b0.y, outB + 2);
    } else if (lane == 63) {
        // out[515..517] = in[510]  (lane63: a1 = in[508..511] -> .z)
        __builtin_nontemporal_store(a1.z, outA + 515);
        __builtin_nontemporal_store(a1.z, outA + 516);
        __builtin_nontemporal_store(a1.z, outA + 517);
        __builtin_nontemporal_store(b1.z, outB + 515);
        __builtin_nontemporal_store(b1.z, outB + 516);
        __builtin_nontemporal_store(b1.z, outB + 517);
    }
}

extern "C" void kernel_launch(void* const* d_in, const int* in_sizes, int n_in,
                              void* d_out, int out_size, void* d_ws, size_t ws_size,
                              hipStream_t stream) {
    const float* x = (const float*)d_in[0];
    float* out = (float*)d_out;
    // total output rows = 16*46*526 = 387,136 = 8 * 48,392
    pad_rows_kernel<<<48392, 256, 0, stream>>>(x, out);
}

// Round 4
// 273.005 us; speedup vs baseline: 1.4173x; 1.4173x over previous
//
#include <hip/hip_runtime.h>

// Output: [16, 46, 526, 518] f32.  Input: [16, 32, 512, 512] f32.
// Per output row (n,c,h):  out_row = [ in[1]x3 , in_row[0..511] , in[510]x3 ]
// where in_row = x[n, cmap(c), hmap(h), :].
//
// R2 layout (128 lanes/row, 4 floats/lane, lane-contiguous wave stores) +
// 2 rows per thread for MLP=2. Regular (cached) stores — R3 showed strided/NT
// partial-line stores regress badly.

using f4 = __attribute__((ext_vector_type(4))) float;

__device__ __forceinline__ int hmap(int d) {
    // reflect(+-2) -> edge(+-2) -> edge(+3 front) -> reflect(+3 front), H=512
    if (d <= 8)   return 2;
    if (d == 9)   return 1;
    if (d <= 521) return d - 10;
    return (d == 522) ? 510 : 509;
}

__device__ __forceinline__ int cmap(int g) {
    // wrap(+-1) -> wrap(+-3) -> edge(+3 back) -> reflect(+3 back), C=32
    if (g >= 43) g = 84 - g;   // reflect back pad (size 43)
    if (g > 39)  g = 39;       // edge clamp (size 40)
    int p = g - 3;             // wrap(+-3) on size 34
    if (p < 0)   p += 34;
    if (p >= 34) p -= 34;
    return (p == 0) ? 31 : ((p <= 32) ? (p - 1) : 0);  // wrap(+-1) on 32
}

__device__ __forceinline__ const float* in_row_ptr(const float* __restrict__ x,
                                                   unsigned int row) {
    const unsigned int nc = row / 526u;          // magic-div
    const int h  = (int)(row - nc * 526u);
    const int c  = (int)(nc % 46u);
    const int n  = (int)(nc / 46u);
    return x + ((((size_t)n * 32 + cmap(c)) * 512 + hmap(h)) << 9);
}

__global__ __launch_bounds__(256) void pad_rows_kernel(const float* __restrict__ x,
                                                       float* __restrict__ out) {
    const int tt   = threadIdx.x & 127;          // lane within row (128 lanes/row)
    const int half = threadIdx.x >> 7;           // 0/1
    const unsigned int base = blockIdx.x * 4u;
    const unsigned int rowA = base + half;       // rows: base, base+1 (spatial)
    const unsigned int rowB = rowA + 2u;         // rows: base+2, base+3 (temporal)

    const float* inA = in_row_ptr(x, rowA);
    const float* inB = in_row_ptr(x, rowB);
    float* outA = out + (size_t)rowA * 518;
    float* outB = out + (size_t)rowB * 518;

    // two independent 16B loads in flight
    const f4 a = reinterpret_cast<const f4*>(inA)[tt];
    const f4 b = reinterpret_cast<const f4*>(inB)[tt];

    // lane-contiguous interior stores (wave covers contiguous 1024B per row)
    *reinterpret_cast<f4*>(outA + 3 + 4 * tt) = a;
    *reinterpret_cast<f4*>(outB + 3 + 4 * tt) = b;

    if (tt == 0) {
        const float ea = a.y, eb = b.y;          // in[1]
        outA[0] = ea; outA[1] = ea; outA[2] = ea;
        outB[0] = eb; outB[1] = eb; outB[2] = eb;
    } else if (tt == 127) {
        const float ea = a.z, eb = b.z;          // in[510]
        outA[515] = ea; outA[516] = ea; outA[517] = ea;
        outB[515] = eb; outB[516] = eb; outB[517] = eb;
    }
}

extern "C" void kernel_launch(void* const* d_in, const int* in_sizes, int n_in,
                              void* d_out, int out_size, void* d_ws, size_t ws_size,
                              hipStream_t stream) {
    const float* x = (const float*)d_in[0];
    float* out = (float*)d_out;
    // total output rows = 16*46*526 = 387,136 = 4 * 96,784
    pad_rows_kernel<<<96784, 256, 0, stream>>>(x, out);
}

// Round 5
// 248.896 us; speedup vs baseline: 1.5546x; 1.0969x over previous
//
#include <hip/hip_runtime.h>

// Output: [16, 46, 526, 518] f32.  Input: [16, 32, 512, 512] f32.
// Per output row (n,c,h):  out_row = [ in[1]x3 , in_row[0..511] , in[510]x3 ]
// where in_row = x[n, cmap(c), hmap(h), :].
//
// R4 structure (128 lanes/row, 4 floats/lane, 2 rows/thread) +
//  - ci-sorted plane processing order (duplicate input planes adjacent in time)
//  - bijective XCD chunk swizzle (each XCD processes 2 whole images -> L2 reuse)

using f4 = __attribute__((ext_vector_type(4))) float;

// processing-order -> output channel c, sorted by ci=cmap(c):
// ci=0:{2,4,36,38} ci=1:{5,39..45} ci=2..29:{6..33} ci=30:{0,34} ci=31:{1,3,35,37}
__device__ const unsigned char cperm_tab[46] = {
    2, 4, 36, 38,
    5, 39, 40, 41, 42, 43, 44, 45,
    6, 7, 8, 9, 10, 11, 12, 13, 14, 15, 16, 17, 18, 19,
    20, 21, 22, 23, 24, 25, 26, 27, 28, 29, 30, 31, 32, 33,
    0, 34,
    1, 3, 35, 37
};

__device__ __forceinline__ int hmap(int d) {
    // reflect(+-2) -> edge(+-2) -> edge(+3 front) -> reflect(+3 front), H=512
    if (d <= 8)   return 2;
    if (d == 9)   return 1;
    if (d <= 521) return d - 10;
    return (d == 522) ? 510 : 509;
}

__device__ __forceinline__ void row_ptrs(const float* __restrict__ x,
                                         float* __restrict__ out,
                                         unsigned int lrow,
                                         const float** pin, float** pout) {
    const unsigned int p  = lrow / 526u;            // logical plane index
    const int          h  = (int)(lrow - p * 526u);
    const unsigned int n  = p / 46u;
    const unsigned int po = p - n * 46u;            // position in ci-sorted order
    const int c = cperm_tab[po];
    int ci;                                          // ci follows from sort order
    if      (po < 4)  ci = 0;
    else if (po < 12) ci = 1;
    else if (po < 40) ci = (int)po - 10;
    else if (po < 42) ci = 30;
    else              ci = 31;
    *pin  = x   + ((((size_t)n * 32 + ci) * 512 + hmap(h)) << 9);
    *pout = out + ((size_t)(n * 46u + (unsigned)c) * 526u + (unsigned)h) * 518u;
}

__global__ __launch_bounds__(256) void pad_rows_kernel(const float* __restrict__ x,
                                                       float* __restrict__ out) {
    // bijective XCD chunk swizzle: 96784 = 8 * 12098 blocks
    const unsigned int d = blockIdx.x;
    const unsigned int l = (d & 7u) * 12098u + (d >> 3);

    const int tt   = threadIdx.x & 127;             // lane within row
    const int half = threadIdx.x >> 7;              // 0/1
    const unsigned int base  = l * 4u;
    const unsigned int lrowA = base + half;
    const unsigned int lrowB = lrowA + 2u;

    const float *inA, *inB;
    float *outA, *outB;
    row_ptrs(x, out, lrowA, &inA, &outA);
    row_ptrs(x, out, lrowB, &inB, &outB);

    // two independent 16B loads in flight
    const f4 a = reinterpret_cast<const f4*>(inA)[tt];
    const f4 b = reinterpret_cast<const f4*>(inB)[tt];

    // lane-contiguous interior stores
    *reinterpret_cast<f4*>(outA + 3 + 4 * tt) = a;
    *reinterpret_cast<f4*>(outB + 3 + 4 * tt) = b;

    if (tt == 0) {
        const float ea = a.y, eb = b.y;             // in[1]
        outA[0] = ea; outA[1] = ea; outA[2] = ea;
        outB[0] = eb; outB[1] = eb; outB[2] = eb;
    } else if (tt == 127) {
        const float ea = a.z, eb = b.z;             // in[510]
        outA[515] = ea; outA[516] = ea; outA[517] = ea;
        outB[515] = eb; outB[516] = eb; outB[517] = eb;
    }
}

extern "C" void kernel_launch(void* const* d_in, const int* in_sizes, int n_in,
                              void* d_out, int out_size, void* d_ws, size_t ws_size,
                              hipStream_t stream) {
    const float* x = (const float*)d_in[0];
    float* out = (float*)d_out;
    // total output rows = 16*46*526 = 387,136 = 4 * 96,784
    pad_rows_kernel<<<96784, 256, 0, stream>>>(x, out);
}